// Round 7
// baseline (601.801 us; speedup 1.0000x reference)
//
#include <hip/hip_runtime.h>

// LSTM: B=2048, T=512, D=1, H=50, OUT=3, fp32.
// One wave64 per block, one batch element per wave (2048 waves = 2/SIMD).
// Lane j owns hidden unit j; 200 recurrent weights resident per lane.
//
// R1-R6 forensics: busy-cycle accounting shows EXACTLY ~1 phantom VALU instr
// per weight-use per step (R6: 220 @200w, R5: ~170 @100w) -> the allocator
// homes the weights in AGPRs (VGPR_Count 108-112 arch, no scratch/HBM
// traffic) and ordinary VALU can't read AGPRs -> one v_accvgpr_read per use.
// The compiler is already at that floor (1070 predicted vs 1110 measured).
// Fix: FORBID AGPR allocation (amdgpu_num_agpr(0) / amdgpu_agpr_alloc(0),
// __has_attribute-guarded) + waves_per_eu(1,2): 256-reg/wave budget, all
// arch -> weights become direct v_fmac operands, phantom reads vanish.

#define BB   2048
#define TT   512
#define HH   50

#if __has_attribute(amdgpu_num_agpr)
#define AGPR_ATTR __attribute__((amdgpu_num_agpr(0)))
#elif __has_attribute(amdgpu_agpr_alloc)
#define AGPR_ATTR __attribute__((amdgpu_agpr_alloc(0)))
#else
#define AGPR_ATTR
#endif

__device__ __forceinline__ float readlane_f(float v, int lane) {
    union { float f; int i; } u;
    u.f = v;
    u.i = __builtin_amdgcn_readlane(u.i, lane);
    return u.f;
}

__device__ __forceinline__ float fast_sigmoid(float x) {
    float e = __builtin_amdgcn_exp2f(-1.4426950408889634f * x);
    return __builtin_amdgcn_rcpf(1.0f + e);
}

__device__ __forceinline__ float fast_tanh(float x) {
    float e = __builtin_amdgcn_exp2f(-2.8853900817779268f * x);  // e^{-2x}
    return __builtin_amdgcn_rcpf(1.0f + e) * 2.0f - 1.0f;
}

// Opaque register pin: keeps the load hoisted and non-rematerializable.
#define PIN(v) asm("" : "+v"(v))

// Apply macro M to k = 0..49
#define REPK(M) \
  M(0)  M(1)  M(2)  M(3)  M(4)  M(5)  M(6)  M(7)  M(8)  M(9)  \
  M(10) M(11) M(12) M(13) M(14) M(15) M(16) M(17) M(18) M(19) \
  M(20) M(21) M(22) M(23) M(24) M(25) M(26) M(27) M(28) M(29) \
  M(30) M(31) M(32) M(33) M(34) M(35) M(36) M(37) M(38) M(39) \
  M(40) M(41) M(42) M(43) M(44) M(45) M(46) M(47) M(48) M(49)

__global__ __launch_bounds__(64)
__attribute__((amdgpu_waves_per_eu(1, 2)))
AGPR_ATTR
void lstm_scan_kernel(const float* __restrict__ x,
                      const float* __restrict__ W_ih,
                      const float* __restrict__ W_hh,
                      const float* __restrict__ b_ih,
                      const float* __restrict__ b_hh,
                      const float* __restrict__ fc_w,
                      const float* __restrict__ fc_b,
                      float* __restrict__ out) {
    __shared__ float xs[TT];     // this wave's x row (2 KB)

    const int lane = threadIdx.x;    // block == one wave
    const int b    = blockIdx.x;

    // Stage x row with float4 loads (2 x 1KB coalesced instructions)
    const float4* xg  = (const float4*)(x + b * TT);
    float4*       xs4 = (float4*)xs;
    xs4[lane]      = xg[lane];
    xs4[lane + 64] = xg[lane + 64];
    __syncthreads();

    const int j = (lane < HH) ? lane : (HH - 1);   // clamp idle lanes

    // 200 weight scalars, loaded once, pinned.
#define WDECL(k) \
    float w0_##k = W_hh[(0 * HH + j) * HH + (k)]; \
    float w1_##k = W_hh[(1 * HH + j) * HH + (k)]; \
    float w2_##k = W_hh[(2 * HH + j) * HH + (k)]; \
    float w3_##k = W_hh[(3 * HH + j) * HH + (k)];
    REPK(WDECL)
#undef WDECL
#define WPIN(k) \
    PIN(w0_##k); PIN(w1_##k); PIN(w2_##k); PIN(w3_##k);
    REPK(WPIN)
#undef WPIN

    float wi0 = W_ih[0 * HH + j];
    float wi1 = W_ih[1 * HH + j];
    float wi2 = W_ih[2 * HH + j];
    float wi3 = W_ih[3 * HH + j];
    float bs0 = b_ih[0 * HH + j] + b_hh[0 * HH + j];
    float bs1 = b_ih[1 * HH + j] + b_hh[1 * HH + j];
    float bs2 = b_ih[2 * HH + j] + b_hh[2 * HH + j];
    float bs3 = b_ih[3 * HH + j] + b_hh[3 * HH + j];
    PIN(wi0); PIN(wi1); PIN(wi2); PIN(wi3);
    PIN(bs0); PIN(bs1); PIN(bs2); PIN(bs3);

    float h = 0.0f, c = 0.0f;

    float xc = xs[0];                    // software-pipelined x read
    #pragma unroll 1
    for (int t = 0; t < TT; ++t) {
        const float xn = xs[(t + 1) & (TT - 1)];   // prefetch next step
        float ai = fmaf(xc, wi0, bs0);
        float af = fmaf(xc, wi1, bs1);
        float ag = fmaf(xc, wi2, bs2);
        float ao = fmaf(xc, wi3, bs3);
#define KSTEP(k) { \
        const float hk = readlane_f(h, k); \
        ai = fmaf(hk, w0_##k, ai); \
        af = fmaf(hk, w1_##k, af); \
        ag = fmaf(hk, w2_##k, ag); \
        ao = fmaf(hk, w3_##k, ao); }
        REPK(KSTEP)
#undef KSTEP
        const float ig = fast_sigmoid(ai);
        const float fg = fast_sigmoid(af);
        const float gg = fast_tanh(ag);
        const float og = fast_sigmoid(ao);
        c = fmaf(fg, c, ig * gg);
        h = og * fast_tanh(c);
        xc = xn;
    }

    // Epilogue: out[b][o] = sum_j h_j * fc_w[o][j] + fc_b[o]
    const float hv = (lane < HH) ? h : 0.0f;
    float r0 = hv * fc_w[0 * HH + j];
    float r1 = hv * fc_w[1 * HH + j];
    float r2 = hv * fc_w[2 * HH + j];
    #pragma unroll
    for (int off = 32; off > 0; off >>= 1) {
        r0 += __shfl_down(r0, off, 64);
        r1 += __shfl_down(r1, off, 64);
        r2 += __shfl_down(r2, off, 64);
    }
    if (lane == 0) {
        out[b * 3 + 0] = r0 + fc_b[0];
        out[b * 3 + 1] = r1 + fc_b[1];
        out[b * 3 + 2] = r2 + fc_b[2];
    }
}

extern "C" void kernel_launch(void* const* d_in, const int* in_sizes, int n_in,
                              void* d_out, int out_size, void* d_ws, size_t ws_size,
                              hipStream_t stream) {
    const float* x    = (const float*)d_in[0];
    const float* W_ih = (const float*)d_in[1];
    const float* W_hh = (const float*)d_in[2];
    const float* b_ih = (const float*)d_in[3];
    const float* b_hh = (const float*)d_in[4];
    const float* fc_w = (const float*)d_in[5];
    const float* fc_b = (const float*)d_in[6];
    float* out = (float*)d_out;

    dim3 grid(BB);       // one wave64 block per batch element
    dim3 block(64);
    lstm_scan_kernel<<<grid, block, 0, stream>>>(x, W_ih, W_hh, b_ih, b_hh,
                                                 fc_w, fc_b, out);
}